// Round 2
// baseline (44.489 us; speedup 1.0000x reference)
//
#include <hip/hip_runtime.h>
#include <math.h>

#define BATCH   128     // rows per block
#define STRIDE  33      // 32 + 1 pad -> conflict-free LDS
#define NBINS   1024

// Custom zero kernel: hipMemsetAsync's fillBufferAligned costs ~39us/replay
// (measured R1); a 1-block kernel writing 4KB costs ~1.5us.
__global__ __launch_bounds__(256) void zero_kernel(float* __restrict__ gC)
{
    const int tid = threadIdx.x;
    #pragma unroll
    for (int k = 0; k < NBINS / 256; ++k)
        gC[tid + k * 256] = 0.0f;
}

__global__ __launch_bounds__(128, 2) void hist_kernel(const float* __restrict__ act,
                                                      float* __restrict__ gC,
                                                      int rows)
{
    __shared__ float Phi_s[BATCH * STRIDE];
    __shared__ float Plo_s[BATCH * STRIDE];
    __shared__ float C_lds[NBINS];

    const int tid = threadIdx.x;

    // zero the block-level C accumulator (covered by the barrier below)
    #pragma unroll
    for (int k = 0; k < NBINS / BATCH; ++k)
        C_lds[tid + k * BATCH] = 0.0f;

    const int row = blockIdx.x * BATCH + tid;

    float v[10];
    float valid = 1.0f;
    if (row < rows) {
        const float* a = act + (size_t)row * 10;
        #pragma unroll
        for (int k = 0; k < 10; ++k) v[k] = a[k];
    } else {
        valid = 0.0f;
        #pragma unroll
        for (int k = 0; k < 10; ++k) v[k] = 0.0f;
    }

    // Product trees. r=0 is the MSB of the 10-bit joint index.
    // hi covers r=0..4, lo covers r=5..9; joint idx = hi*32 + lo.
    float hi[32], lo[32];
    {
        float t2[2], t4[4], t8[8], t16[16];
        t2[0] = valid * (1.0f - v[0]); t2[1] = valid * v[0];
        #pragma unroll
        for (int k = 0; k < 4; ++k)  t4[k]  = t2[k >> 1]  * ((k & 1) ? v[1] : 1.0f - v[1]);
        #pragma unroll
        for (int k = 0; k < 8; ++k)  t8[k]  = t4[k >> 1]  * ((k & 1) ? v[2] : 1.0f - v[2]);
        #pragma unroll
        for (int k = 0; k < 16; ++k) t16[k] = t8[k >> 1]  * ((k & 1) ? v[3] : 1.0f - v[3]);
        #pragma unroll
        for (int k = 0; k < 32; ++k) hi[k]  = t16[k >> 1] * ((k & 1) ? v[4] : 1.0f - v[4]);
    }
    {
        float t2[2], t4[4], t8[8], t16[16];
        t2[0] = 1.0f - v[5]; t2[1] = v[5];
        #pragma unroll
        for (int k = 0; k < 4; ++k)  t4[k]  = t2[k >> 1]  * ((k & 1) ? v[6] : 1.0f - v[6]);
        #pragma unroll
        for (int k = 0; k < 8; ++k)  t8[k]  = t4[k >> 1]  * ((k & 1) ? v[7] : 1.0f - v[7]);
        #pragma unroll
        for (int k = 0; k < 16; ++k) t16[k] = t8[k >> 1]  * ((k & 1) ? v[8] : 1.0f - v[8]);
        #pragma unroll
        for (int k = 0; k < 32; ++k) lo[k]  = t16[k >> 1] * ((k & 1) ? v[9] : 1.0f - v[9]);
    }

    // stage to LDS (stride 33: bank = (tid + k) % 32 -> 2 lanes/bank, free)
    #pragma unroll
    for (int k = 0; k < 32; ++k) Phi_s[tid * STRIDE + k] = hi[k];
    #pragma unroll
    for (int k = 0; k < 32; ++k) Plo_s[tid * STRIDE + k] = lo[k];

    __syncthreads();

    // Phase 2: C[32][32] += Phi^T Plo over the batch.
    // 64 lanes = 8x8 grid of 4x4 register tiles (covers all 1024 entries).
    // Wave w handles rows r == w (mod 2).
    const int wave = tid >> 6;
    const int lane = tid & 63;
    const int i0 = (lane >> 3) * 4;
    const int j0 = (lane & 7) * 4;

    float c[4][4];
    #pragma unroll
    for (int ii = 0; ii < 4; ++ii)
        #pragma unroll
        for (int jj = 0; jj < 4; ++jj) c[ii][jj] = 0.0f;

    for (int t = 0; t < BATCH / 2; ++t) {
        const int r = t * 2 + wave;
        const int base = r * STRIDE;
        float ph[4], pl[4];
        #pragma unroll
        for (int k = 0; k < 4; ++k) ph[k] = Phi_s[base + i0 + k];
        #pragma unroll
        for (int k = 0; k < 4; ++k) pl[k] = Plo_s[base + j0 + k];
        #pragma unroll
        for (int ii = 0; ii < 4; ++ii)
            #pragma unroll
            for (int jj = 0; jj < 4; ++jj)
                c[ii][jj] = fmaf(ph[ii], pl[jj], c[ii][jj]);
    }

    // block-level reduce across the 2 waves
    #pragma unroll
    for (int ii = 0; ii < 4; ++ii)
        #pragma unroll
        for (int jj = 0; jj < 4; ++jj)
            atomicAdd(&C_lds[(i0 + ii) * 32 + (j0 + jj)], c[ii][jj]);

    __syncthreads();

    // one global atomic pass per block
    #pragma unroll
    for (int k = 0; k < NBINS / BATCH; ++k) {
        const int e = tid + k * BATCH;
        atomicAdd(&gC[e], C_lds[e]);
    }
}

__global__ __launch_bounds__(256) void finalize_kernel(const float* __restrict__ gC,
                                                       float* __restrict__ out,
                                                       float invB)
{
    __shared__ float red[4];
    const int tid = threadIdx.x;
    float s = 0.0f;
    #pragma unroll
    for (int k = 0; k < 4; ++k) {
        const float p  = gC[tid * 4 + k] * invB;
        const float ps = fmaxf(p, 1e-12f);
        s += p * log2f(ps);   // out = sum p * log2(clip(p)) = -joint_h
    }
    #pragma unroll
    for (int off = 32; off > 0; off >>= 1) s += __shfl_down(s, off);
    if ((tid & 63) == 0) red[tid >> 6] = s;
    __syncthreads();
    if (tid == 0) out[0] = red[0] + red[1] + red[2] + red[3];
}

extern "C" void kernel_launch(void* const* d_in, const int* in_sizes, int n_in,
                              void* d_out, int out_size, void* d_ws, size_t ws_size,
                              hipStream_t stream)
{
    const float* act = (const float*)d_in[0];
    const int rows = in_sizes[0] / 10;   // B = 131072
    float* gC = (float*)d_ws;            // 1024-float accumulator

    // d_ws is poisoned (0xAA) and never re-poisoned: zero it every call with
    // our own kernel (hipMemsetAsync's fill kernel measured ~39us/replay).
    zero_kernel<<<1, 256, 0, stream>>>(gC);

    const int grid = (rows + BATCH - 1) / BATCH;   // 1024 blocks
    hist_kernel<<<grid, 128, 0, stream>>>(act, gC, rows);
    finalize_kernel<<<1, 256, 0, stream>>>(gC, (float*)d_out, 1.0f / (float)rows);
}

// Round 3
// 44.463 us; speedup vs baseline: 1.0006x; 1.0006x over previous
//
#include <hip/hip_runtime.h>
#include <math.h>

#define BATCH   128     // rows per block
#define STRIDE  34      // dwords; 34 = 2 mod 32 -> <=2-way write conflicts (free),
                        // broadcast reads conflict-free; 136B rows keep 16B align on even rows
#define NBINS   1024

// Custom zero kernel: hipMemsetAsync's fillBufferAligned is slow/artifact-prone.
__global__ __launch_bounds__(256) void zero_kernel(float* __restrict__ gC)
{
    const int tid = threadIdx.x;
    #pragma unroll
    for (int k = 0; k < NBINS / 256; ++k)
        gC[tid + k * 256] = 0.0f;
}

__global__ __launch_bounds__(128, 2) void hist_kernel(const float* __restrict__ act,
                                                      float* __restrict__ gC,
                                                      int rows)
{
    __shared__ __align__(16) float Phi_s[BATCH * STRIDE];
    __shared__ __align__(16) float Plo_s[BATCH * STRIDE];
    __shared__ float C_lds[NBINS];

    const int tid = threadIdx.x;

    // zero the block-level C accumulator (covered by the barrier below)
    #pragma unroll
    for (int k = 0; k < NBINS / BATCH; ++k)
        C_lds[tid + k * BATCH] = 0.0f;

    const int row = blockIdx.x * BATCH + tid;

    float v[10];
    float valid = 1.0f;
    if (row < rows) {
        // 40B row, 8B-aligned -> 5x float2 vector loads
        const float2* a2 = (const float2*)(act + (size_t)row * 10);
        #pragma unroll
        for (int k = 0; k < 5; ++k) {
            float2 t = a2[k];
            v[2 * k] = t.x; v[2 * k + 1] = t.y;
        }
    } else {
        valid = 0.0f;
        #pragma unroll
        for (int k = 0; k < 10; ++k) v[k] = 0.0f;
    }

    // Product trees. r=0 is the MSB of the 10-bit joint index.
    // hi covers r=0..4, lo covers r=5..9; joint idx = hi*32 + lo.
    float hi[32], lo[32];
    {
        float t2[2], t4[4], t8[8], t16[16];
        t2[0] = valid * (1.0f - v[0]); t2[1] = valid * v[0];
        #pragma unroll
        for (int k = 0; k < 4; ++k)  t4[k]  = t2[k >> 1]  * ((k & 1) ? v[1] : 1.0f - v[1]);
        #pragma unroll
        for (int k = 0; k < 8; ++k)  t8[k]  = t4[k >> 1]  * ((k & 1) ? v[2] : 1.0f - v[2]);
        #pragma unroll
        for (int k = 0; k < 16; ++k) t16[k] = t8[k >> 1]  * ((k & 1) ? v[3] : 1.0f - v[3]);
        #pragma unroll
        for (int k = 0; k < 32; ++k) hi[k]  = t16[k >> 1] * ((k & 1) ? v[4] : 1.0f - v[4]);
    }
    {
        float t2[2], t4[4], t8[8], t16[16];
        t2[0] = 1.0f - v[5]; t2[1] = v[5];
        #pragma unroll
        for (int k = 0; k < 4; ++k)  t4[k]  = t2[k >> 1]  * ((k & 1) ? v[6] : 1.0f - v[6]);
        #pragma unroll
        for (int k = 0; k < 8; ++k)  t8[k]  = t4[k >> 1]  * ((k & 1) ? v[7] : 1.0f - v[7]);
        #pragma unroll
        for (int k = 0; k < 16; ++k) t16[k] = t8[k >> 1]  * ((k & 1) ? v[8] : 1.0f - v[8]);
        #pragma unroll
        for (int k = 0; k < 32; ++k) lo[k]  = t16[k >> 1] * ((k & 1) ? v[9] : 1.0f - v[9]);
    }

    // stage to LDS with float2 writes (8B-aligned for every row: 136*tid % 8 == 0)
    {
        float2* ph2 = (float2*)&Phi_s[tid * STRIDE];
        float2* pl2 = (float2*)&Plo_s[tid * STRIDE];
        #pragma unroll
        for (int k = 0; k < 16; ++k) ph2[k] = make_float2(hi[2 * k], hi[2 * k + 1]);
        #pragma unroll
        for (int k = 0; k < 16; ++k) pl2[k] = make_float2(lo[2 * k], lo[2 * k + 1]);
    }

    __syncthreads();

    // Phase 2: C[32][32] += Phi^T Plo over the batch.
    // 64 lanes = 8x8 grid of 4x4 register tiles. Wave w handles rows r == w (mod 2).
    const int wave = tid >> 6;
    const int lane = tid & 63;
    const int i0 = (lane >> 3) * 4;
    const int j0 = (lane & 7) * 4;

    float c[4][4];
    #pragma unroll
    for (int ii = 0; ii < 4; ++ii)
        #pragma unroll
        for (int jj = 0; jj < 4; ++jj) c[ii][jj] = 0.0f;

    if (wave == 0) {
        // even rows: 136*r % 16 == 0 -> float4 LDS reads (1 per operand per row)
        for (int t = 0; t < BATCH / 2; ++t) {
            const int base = (2 * t) * STRIDE;
            const float4 ph = *(const float4*)&Phi_s[base + i0];
            const float4 pl = *(const float4*)&Plo_s[base + j0];
            const float phv[4] = {ph.x, ph.y, ph.z, ph.w};
            const float plv[4] = {pl.x, pl.y, pl.z, pl.w};
            #pragma unroll
            for (int ii = 0; ii < 4; ++ii)
                #pragma unroll
                for (int jj = 0; jj < 4; ++jj)
                    c[ii][jj] = fmaf(phv[ii], plv[jj], c[ii][jj]);
        }
    } else {
        // odd rows: 8B-aligned -> float2 LDS reads (2 per operand per row)
        for (int t = 0; t < BATCH / 2; ++t) {
            const int base = (2 * t + 1) * STRIDE;
            const float2 pha = *(const float2*)&Phi_s[base + i0];
            const float2 phb = *(const float2*)&Phi_s[base + i0 + 2];
            const float2 pla = *(const float2*)&Plo_s[base + j0];
            const float2 plb = *(const float2*)&Plo_s[base + j0 + 2];
            const float phv[4] = {pha.x, pha.y, phb.x, phb.y};
            const float plv[4] = {pla.x, pla.y, plb.x, plb.y};
            #pragma unroll
            for (int ii = 0; ii < 4; ++ii)
                #pragma unroll
                for (int jj = 0; jj < 4; ++jj)
                    c[ii][jj] = fmaf(phv[ii], plv[jj], c[ii][jj]);
        }
    }

    // block-level reduce across the 2 waves
    #pragma unroll
    for (int ii = 0; ii < 4; ++ii)
        #pragma unroll
        for (int jj = 0; jj < 4; ++jj)
            atomicAdd(&C_lds[(i0 + ii) * 32 + (j0 + jj)], c[ii][jj]);

    __syncthreads();

    // one global atomic pass per block
    #pragma unroll
    for (int k = 0; k < NBINS / BATCH; ++k) {
        const int e = tid + k * BATCH;
        atomicAdd(&gC[e], C_lds[e]);
    }
}

__global__ __launch_bounds__(256) void finalize_kernel(const float* __restrict__ gC,
                                                       float* __restrict__ out,
                                                       float invB)
{
    __shared__ float red[4];
    const int tid = threadIdx.x;
    float s = 0.0f;
    #pragma unroll
    for (int k = 0; k < 4; ++k) {
        const float p  = gC[tid * 4 + k] * invB;
        const float ps = fmaxf(p, 1e-12f);
        s += p * log2f(ps);   // out = sum p * log2(clip(p)) = -joint_h
    }
    #pragma unroll
    for (int off = 32; off > 0; off >>= 1) s += __shfl_down(s, off);
    if ((tid & 63) == 0) red[tid >> 6] = s;
    __syncthreads();
    if (tid == 0) out[0] = red[0] + red[1] + red[2] + red[3];
}

extern "C" void kernel_launch(void* const* d_in, const int* in_sizes, int n_in,
                              void* d_out, int out_size, void* d_ws, size_t ws_size,
                              hipStream_t stream)
{
    const float* act = (const float*)d_in[0];
    const int rows = in_sizes[0] / 10;   // B = 131072
    float* gC = (float*)d_ws;            // 1024-float accumulator

    zero_kernel<<<1, 256, 0, stream>>>(gC);

    const int grid = (rows + BATCH - 1) / BATCH;   // 1024 blocks
    hist_kernel<<<grid, 128, 0, stream>>>(act, gC, rows);
    finalize_kernel<<<1, 256, 0, stream>>>(gC, (float*)d_out, 1.0f / (float)rows);
}

// Round 4
// 32.026 us; speedup vs baseline: 1.3891x; 1.3883x over previous
//
#include <hip/hip_runtime.h>
#include <math.h>

#define BATCH   128     // rows per block
#define STRIDE  34      // dwords; 2 mod 32 -> <=2-way LDS write conflicts (free)
#define NBINS   1024
#define NSLOT   32      // independent global accumulator copies: spreads the
                        // 1M f32 atomicAdds over 2048 cache lines instead of 64
                        // (same-line atomic serialization was ~4cyc x 16k/line)

__global__ __launch_bounds__(256) void zero_kernel(float* __restrict__ gC)
{
    // zero all NSLOT*NBINS floats (128KB): 32 blocks x 256 threads x float4
    float4* p = (float4*)gC;
    p[blockIdx.x * 256 + threadIdx.x] = make_float4(0.f, 0.f, 0.f, 0.f);
}

__global__ __launch_bounds__(128, 2) void hist_kernel(const float* __restrict__ act,
                                                      float* __restrict__ gC,
                                                      int rows)
{
    __shared__ __align__(16) float Phi_s[BATCH * STRIDE];
    __shared__ __align__(16) float Plo_s[BATCH * STRIDE];
    __shared__ float C_lds[NBINS];

    const int tid = threadIdx.x;

    #pragma unroll
    for (int k = 0; k < NBINS / BATCH; ++k)
        C_lds[tid + k * BATCH] = 0.0f;

    const int row = blockIdx.x * BATCH + tid;

    float v[10];
    float valid = 1.0f;
    if (row < rows) {
        const float2* a2 = (const float2*)(act + (size_t)row * 10);
        #pragma unroll
        for (int k = 0; k < 5; ++k) {
            float2 t = a2[k];
            v[2 * k] = t.x; v[2 * k + 1] = t.y;
        }
    } else {
        valid = 0.0f;
        #pragma unroll
        for (int k = 0; k < 10; ++k) v[k] = 0.0f;
    }

    // Product trees. r=0 is the MSB of the 10-bit joint index.
    float hi[32], lo[32];
    {
        float t2[2], t4[4], t8[8], t16[16];
        t2[0] = valid * (1.0f - v[0]); t2[1] = valid * v[0];
        #pragma unroll
        for (int k = 0; k < 4; ++k)  t4[k]  = t2[k >> 1]  * ((k & 1) ? v[1] : 1.0f - v[1]);
        #pragma unroll
        for (int k = 0; k < 8; ++k)  t8[k]  = t4[k >> 1]  * ((k & 1) ? v[2] : 1.0f - v[2]);
        #pragma unroll
        for (int k = 0; k < 16; ++k) t16[k] = t8[k >> 1]  * ((k & 1) ? v[3] : 1.0f - v[3]);
        #pragma unroll
        for (int k = 0; k < 32; ++k) hi[k]  = t16[k >> 1] * ((k & 1) ? v[4] : 1.0f - v[4]);
    }
    {
        float t2[2], t4[4], t8[8], t16[16];
        t2[0] = 1.0f - v[5]; t2[1] = v[5];
        #pragma unroll
        for (int k = 0; k < 4; ++k)  t4[k]  = t2[k >> 1]  * ((k & 1) ? v[6] : 1.0f - v[6]);
        #pragma unroll
        for (int k = 0; k < 8; ++k)  t8[k]  = t4[k >> 1]  * ((k & 1) ? v[7] : 1.0f - v[7]);
        #pragma unroll
        for (int k = 0; k < 16; ++k) t16[k] = t8[k >> 1]  * ((k & 1) ? v[8] : 1.0f - v[8]);
        #pragma unroll
        for (int k = 0; k < 32; ++k) lo[k]  = t16[k >> 1] * ((k & 1) ? v[9] : 1.0f - v[9]);
    }

    {
        float2* ph2 = (float2*)&Phi_s[tid * STRIDE];
        float2* pl2 = (float2*)&Plo_s[tid * STRIDE];
        #pragma unroll
        for (int k = 0; k < 16; ++k) ph2[k] = make_float2(hi[2 * k], hi[2 * k + 1]);
        #pragma unroll
        for (int k = 0; k < 16; ++k) pl2[k] = make_float2(lo[2 * k], lo[2 * k + 1]);
    }

    __syncthreads();

    // Phase 2: C[32][32] += Phi^T Plo. 64 lanes = 8x8 grid of 4x4 tiles.
    const int wave = tid >> 6;
    const int lane = tid & 63;
    const int i0 = (lane >> 3) * 4;
    const int j0 = (lane & 7) * 4;

    float c[4][4];
    #pragma unroll
    for (int ii = 0; ii < 4; ++ii)
        #pragma unroll
        for (int jj = 0; jj < 4; ++jj) c[ii][jj] = 0.0f;

    if (wave == 0) {
        for (int t = 0; t < BATCH / 2; ++t) {
            const int base = (2 * t) * STRIDE;
            const float4 ph = *(const float4*)&Phi_s[base + i0];
            const float4 pl = *(const float4*)&Plo_s[base + j0];
            const float phv[4] = {ph.x, ph.y, ph.z, ph.w};
            const float plv[4] = {pl.x, pl.y, pl.z, pl.w};
            #pragma unroll
            for (int ii = 0; ii < 4; ++ii)
                #pragma unroll
                for (int jj = 0; jj < 4; ++jj)
                    c[ii][jj] = fmaf(phv[ii], plv[jj], c[ii][jj]);
        }
    } else {
        for (int t = 0; t < BATCH / 2; ++t) {
            const int base = (2 * t + 1) * STRIDE;
            const float2 pha = *(const float2*)&Phi_s[base + i0];
            const float2 phb = *(const float2*)&Phi_s[base + i0 + 2];
            const float2 pla = *(const float2*)&Plo_s[base + j0];
            const float2 plb = *(const float2*)&Plo_s[base + j0 + 2];
            const float phv[4] = {pha.x, pha.y, phb.x, phb.y};
            const float plv[4] = {pla.x, pla.y, plb.x, plb.y};
            #pragma unroll
            for (int ii = 0; ii < 4; ++ii)
                #pragma unroll
                for (int jj = 0; jj < 4; ++jj)
                    c[ii][jj] = fmaf(phv[ii], plv[jj], c[ii][jj]);
        }
    }

    #pragma unroll
    for (int ii = 0; ii < 4; ++ii)
        #pragma unroll
        for (int jj = 0; jj < 4; ++jj)
            atomicAdd(&C_lds[(i0 + ii) * 32 + (j0 + jj)], c[ii][jj]);

    __syncthreads();

    // global atomic pass, spread over NSLOT accumulator copies
    const int slotbase = (blockIdx.x & (NSLOT - 1)) * NBINS;
    #pragma unroll
    for (int k = 0; k < NBINS / BATCH; ++k) {
        const int e = tid + k * BATCH;
        atomicAdd(&gC[slotbase + e], C_lds[e]);
    }
}

__global__ __launch_bounds__(256) void finalize_kernel(const float* __restrict__ gC,
                                                       float* __restrict__ out,
                                                       float invB)
{
    __shared__ float red[4];
    const int tid = threadIdx.x;

    // sum the NSLOT slot copies: thread owns bins 4*tid..4*tid+3
    float4 acc = make_float4(0.f, 0.f, 0.f, 0.f);
    #pragma unroll
    for (int s = 0; s < NSLOT; ++s) {
        const float4 t = *(const float4*)&gC[s * NBINS + tid * 4];
        acc.x += t.x; acc.y += t.y; acc.z += t.z; acc.w += t.w;
    }

    float s = 0.0f;
    const float b[4] = {acc.x, acc.y, acc.z, acc.w};
    #pragma unroll
    for (int k = 0; k < 4; ++k) {
        const float p  = b[k] * invB;
        const float ps = fmaxf(p, 1e-12f);
        s += p * log2f(ps);   // out = sum p*log2(clip(p)) = -joint_h
    }
    #pragma unroll
    for (int off = 32; off > 0; off >>= 1) s += __shfl_down(s, off);
    if ((tid & 63) == 0) red[tid >> 6] = s;
    __syncthreads();
    if (tid == 0) out[0] = red[0] + red[1] + red[2] + red[3];
}

extern "C" void kernel_launch(void* const* d_in, const int* in_sizes, int n_in,
                              void* d_out, int out_size, void* d_ws, size_t ws_size,
                              hipStream_t stream)
{
    const float* act = (const float*)d_in[0];
    const int rows = in_sizes[0] / 10;   // B = 131072
    float* gC = (float*)d_ws;            // NSLOT x NBINS accumulator (128KB)

    zero_kernel<<<NSLOT * NBINS * 4 / (256 * 16), 256, 0, stream>>>(gC);  // 32 blocks

    const int grid = (rows + BATCH - 1) / BATCH;   // 1024 blocks
    hist_kernel<<<grid, 128, 0, stream>>>(act, gC, rows);
    finalize_kernel<<<1, 256, 0, stream>>>(gC, (float*)d_out, 1.0f / (float)rows);
}

// Round 5
// 19.165 us; speedup vs baseline: 2.3214x; 1.6711x over previous
//
#include <hip/hip_runtime.h>
#include <math.h>

#define BATCH   128     // rows per block
#define STRIDE  34      // dwords; 2 mod 32 -> <=2-way LDS write conflicts (free)
#define NBINS   1024
#define NCHUNK  32      // second-level partials: 32 chunks of 32 block-partials

// ws layout: gC[1024*1024] block partials (4MB) | g2[32*1024] chunk partials (128KB)
// No atomics anywhere; every used ws byte is overwritten every call (poison-safe).

__global__ __launch_bounds__(128, 2) void hist_kernel(const float* __restrict__ act,
                                                      float* __restrict__ gC,
                                                      int rows)
{
    __shared__ __align__(16) float Phi_s[BATCH * STRIDE];
    __shared__ __align__(16) float Plo_s[BATCH * STRIDE];
    __shared__ __align__(16) float C_lds[NBINS];

    const int tid = threadIdx.x;
    const int row = blockIdx.x * BATCH + tid;

    float v[10];
    float valid = 1.0f;
    if (row < rows) {
        const float2* a2 = (const float2*)(act + (size_t)row * 10);
        #pragma unroll
        for (int k = 0; k < 5; ++k) {
            float2 t = a2[k];
            v[2 * k] = t.x; v[2 * k + 1] = t.y;
        }
    } else {
        valid = 0.0f;
        #pragma unroll
        for (int k = 0; k < 10; ++k) v[k] = 0.0f;
    }

    // Product trees. r=0 is the MSB of the 10-bit joint index.
    float hi[32], lo[32];
    {
        float t2[2], t4[4], t8[8], t16[16];
        t2[0] = valid * (1.0f - v[0]); t2[1] = valid * v[0];
        #pragma unroll
        for (int k = 0; k < 4; ++k)  t4[k]  = t2[k >> 1]  * ((k & 1) ? v[1] : 1.0f - v[1]);
        #pragma unroll
        for (int k = 0; k < 8; ++k)  t8[k]  = t4[k >> 1]  * ((k & 1) ? v[2] : 1.0f - v[2]);
        #pragma unroll
        for (int k = 0; k < 16; ++k) t16[k] = t8[k >> 1]  * ((k & 1) ? v[3] : 1.0f - v[3]);
        #pragma unroll
        for (int k = 0; k < 32; ++k) hi[k]  = t16[k >> 1] * ((k & 1) ? v[4] : 1.0f - v[4]);
    }
    {
        float t2[2], t4[4], t8[8], t16[16];
        t2[0] = 1.0f - v[5]; t2[1] = v[5];
        #pragma unroll
        for (int k = 0; k < 4; ++k)  t4[k]  = t2[k >> 1]  * ((k & 1) ? v[6] : 1.0f - v[6]);
        #pragma unroll
        for (int k = 0; k < 8; ++k)  t8[k]  = t4[k >> 1]  * ((k & 1) ? v[7] : 1.0f - v[7]);
        #pragma unroll
        for (int k = 0; k < 16; ++k) t16[k] = t8[k >> 1]  * ((k & 1) ? v[8] : 1.0f - v[8]);
        #pragma unroll
        for (int k = 0; k < 32; ++k) lo[k]  = t16[k >> 1] * ((k & 1) ? v[9] : 1.0f - v[9]);
    }

    {
        float2* ph2 = (float2*)&Phi_s[tid * STRIDE];
        float2* pl2 = (float2*)&Plo_s[tid * STRIDE];
        #pragma unroll
        for (int k = 0; k < 16; ++k) ph2[k] = make_float2(hi[2 * k], hi[2 * k + 1]);
        #pragma unroll
        for (int k = 0; k < 16; ++k) pl2[k] = make_float2(lo[2 * k], lo[2 * k + 1]);
    }

    __syncthreads();

    // Phase 2: C[32][32] += Phi^T Plo. 64 lanes = 8x8 grid of 4x4 tiles.
    const int wave = tid >> 6;
    const int lane = tid & 63;
    const int i0 = (lane >> 3) * 4;
    const int j0 = (lane & 7) * 4;

    float c[4][4];
    #pragma unroll
    for (int ii = 0; ii < 4; ++ii)
        #pragma unroll
        for (int jj = 0; jj < 4; ++jj) c[ii][jj] = 0.0f;

    if (wave == 0) {
        for (int t = 0; t < BATCH / 2; ++t) {
            const int base = (2 * t) * STRIDE;
            const float4 ph = *(const float4*)&Phi_s[base + i0];
            const float4 pl = *(const float4*)&Plo_s[base + j0];
            const float phv[4] = {ph.x, ph.y, ph.z, ph.w};
            const float plv[4] = {pl.x, pl.y, pl.z, pl.w};
            #pragma unroll
            for (int ii = 0; ii < 4; ++ii)
                #pragma unroll
                for (int jj = 0; jj < 4; ++jj)
                    c[ii][jj] = fmaf(phv[ii], plv[jj], c[ii][jj]);
        }
    } else {
        for (int t = 0; t < BATCH / 2; ++t) {
            const int base = (2 * t + 1) * STRIDE;
            const float2 pha = *(const float2*)&Phi_s[base + i0];
            const float2 phb = *(const float2*)&Phi_s[base + i0 + 2];
            const float2 pla = *(const float2*)&Plo_s[base + j0];
            const float2 plb = *(const float2*)&Plo_s[base + j0 + 2];
            const float phv[4] = {pha.x, pha.y, phb.x, phb.y};
            const float plv[4] = {pla.x, pla.y, plb.x, plb.y};
            #pragma unroll
            for (int ii = 0; ii < 4; ++ii)
                #pragma unroll
                for (int jj = 0; jj < 4; ++jj)
                    c[ii][jj] = fmaf(phv[ii], plv[jj], c[ii][jj]);
        }
    }

    // block-level reduce without atomics: wave1 stores, wave0 accumulates
    if (wave == 1) {
        #pragma unroll
        for (int ii = 0; ii < 4; ++ii)
            #pragma unroll
            for (int jj = 0; jj < 4; ++jj)
                C_lds[(i0 + ii) * 32 + (j0 + jj)] = c[ii][jj];
    }
    __syncthreads();
    if (wave == 0) {
        #pragma unroll
        for (int ii = 0; ii < 4; ++ii)
            #pragma unroll
            for (int jj = 0; jj < 4; ++jj) {
                const int e = (i0 + ii) * 32 + (j0 + jj);
                C_lds[e] += c[ii][jj];
            }
    }
    __syncthreads();

    // coalesced plain-store of the block's 4KB partial (NO global atomics)
    float4* dst4 = (float4*)(gC + (size_t)blockIdx.x * NBINS);
    const float4* src4 = (const float4*)C_lds;
    dst4[tid]       = src4[tid];
    dst4[tid + 128] = src4[tid + 128];
}

// Sum 1024 block-partials -> 32 chunk-partials. 128 blocks x 256 threads.
__global__ __launch_bounds__(256) void reduce_kernel(const float* __restrict__ gC,
                                                     float* __restrict__ g2)
{
    const int chunk = blockIdx.x >> 2;                    // 0..31
    const int bin   = (blockIdx.x & 3) * 256 + threadIdx.x;
    const float* p  = gC + (size_t)chunk * 32 * NBINS + bin;
    float s = 0.0f;
    #pragma unroll
    for (int k = 0; k < 32; ++k) s += p[k * NBINS];       // coalesced across threads
    g2[chunk * NBINS + bin] = s;
}

__global__ __launch_bounds__(256) void finalize_kernel(const float* __restrict__ g2,
                                                       float* __restrict__ out,
                                                       float invB)
{
    __shared__ float red[4];
    const int tid = threadIdx.x;

    float4 acc = make_float4(0.f, 0.f, 0.f, 0.f);
    #pragma unroll
    for (int s = 0; s < NCHUNK; ++s) {
        const float4 t = *(const float4*)&g2[s * NBINS + tid * 4];
        acc.x += t.x; acc.y += t.y; acc.z += t.z; acc.w += t.w;
    }

    float s = 0.0f;
    const float b[4] = {acc.x, acc.y, acc.z, acc.w};
    #pragma unroll
    for (int k = 0; k < 4; ++k) {
        const float p  = b[k] * invB;
        const float ps = fmaxf(p, 1e-12f);
        s += p * log2f(ps);   // out = sum p*log2(clip(p)) = -joint_h
    }
    #pragma unroll
    for (int off = 32; off > 0; off >>= 1) s += __shfl_down(s, off);
    if ((tid & 63) == 0) red[tid >> 6] = s;
    __syncthreads();
    if (tid == 0) out[0] = red[0] + red[1] + red[2] + red[3];
}

extern "C" void kernel_launch(void* const* d_in, const int* in_sizes, int n_in,
                              void* d_out, int out_size, void* d_ws, size_t ws_size,
                              hipStream_t stream)
{
    const float* act = (const float*)d_in[0];
    const int rows = in_sizes[0] / 10;        // B = 131072
    float* gC = (float*)d_ws;                 // 1024 x 1024 block partials (4MB)
    float* g2 = gC + 1024 * NBINS;            // 32 x 1024 chunk partials (128KB)

    const int grid = (rows + BATCH - 1) / BATCH;   // 1024 blocks
    hist_kernel<<<grid, 128, 0, stream>>>(act, gC, rows);
    reduce_kernel<<<128, 256, 0, stream>>>(gC, g2);
    finalize_kernel<<<1, 256, 0, stream>>>(g2, (float*)d_out, 1.0f / (float)rows);
}